// Round 1
// 4786.414 us; speedup vs baseline: 2.6244x; 2.6244x over previous
//
#include <hip/hip_runtime.h>

// LeNet C3 connectivity: for each input channel, the 10 output channels it feeds.
constexpr int CL[6][10] = {
    {0, 4, 5, 6, 9, 10, 11, 12, 14, 15},   // cin 0
    {0, 1, 5, 6, 7, 10, 11, 12, 13, 15},   // cin 1
    {0, 1, 2, 6, 7, 8, 11, 13, 14, 15},    // cin 2
    {1, 2, 3, 6, 7, 8, 9, 12, 14, 15},     // cin 3
    {2, 3, 4, 7, 8, 9, 10, 12, 13, 15},    // cin 4
    {3, 4, 5, 8, 9, 10, 11, 13, 14, 15},   // cin 5
};

#define CIN   6
#define COUT  16
#define HW    512
#define TILE_W 64
#define TILE_H 16
#define IN_W  68   // TILE_W + 4 halo
#define IN_H  20   // TILE_H + 4 halo
#define BIAS_OFF 1536  // float offset of bias within d_ws

// ---- Forced compile-time unrolling machinery -------------------------------
// #pragma unroll is a heuristic; it silently failed on the 6000-FMA body and
// left CL[cin][j] runtime -> acc[][] runtime-indexed -> scratch (VGPR=44,
// 48 GB of spill writes). Template recursion makes every index a structural
// compile-time constant: the compiler CANNOT leave it rolled.
template<int V> struct Ic { static constexpr int value = V; };

template<int N> struct U {
    template<class F>
    static __device__ __forceinline__ void run(F&& f) {
        U<N - 1>::run(f);
        f(Ic<N - 1>{});
    }
};
template<> struct U<0> {
    template<class F>
    static __device__ __forceinline__ void run(F&&) {}
};

// Pack masked weights into ws as wpk[cin][dx][dy][j(0..9)] (1500 floats),
// bias at float offset 1536 (16 floats). All-uniform layout so the main
// kernel's weight reads are scalar (SGPR) loads.
__global__ void pack_weights(const float* __restrict__ W,
                             const float* __restrict__ b,
                             const int* __restrict__ mask,
                             float* __restrict__ ws) {
    int i = blockIdx.x * blockDim.x + threadIdx.x;
    if (i < 1500) {
        int cin = i / 250;
        int r   = i % 250;
        int dx  = r / 50;
        int r2  = r % 50;
        int dy  = r2 / 10;
        int j   = r2 % 10;
        int cout = CL[cin][j];
        float v = W[((cout * CIN + cin) * 5 + dy) * 5 + dx]
                  * (float)mask[cout * CIN + cin];
        ws[((cin * 5 + dx) * 5 + dy) * 10 + j] = v;
    } else if (i >= BIAS_OFF && i < BIAS_OFF + COUT) {
        ws[i] = b[i - BIAS_OFF];
    }
}

__global__ __launch_bounds__(256, 2)
void conv_main(const float* __restrict__ x,
               const float* __restrict__ ws,
               float* __restrict__ out) {
    __shared__ float tile[CIN * IN_H * IN_W];  // 8160 floats = 32640 B

    const int tid = threadIdx.x;
    const int bw0 = blockIdx.x * TILE_W;
    const int bh0 = blockIdx.y * TILE_H;
    const int b   = blockIdx.z;

    // ---- Stage input tile (all 6 channels, with 2-wide zero halo) ----
    const float* xb = x + (size_t)b * CIN * HW * HW;
    for (int idx = tid; idx < CIN * IN_H * IN_W; idx += 256) {
        int c   = idx % IN_W;
        int t   = idx / IN_W;
        int row = t % IN_H;
        int cin = t / IN_H;
        int gh = bh0 + row - 2;
        int gw = bw0 + c - 2;
        float v = 0.f;
        if ((unsigned)gh < (unsigned)HW && (unsigned)gw < (unsigned)HW)
            v = xb[((size_t)cin * HW + gh) * HW + gw];
        tile[idx] = v;
    }
    __syncthreads();

    // ---- Compute: each thread = 1 column (w) x 4 output rows x 16 couts ----
    const int w  = tid & 63;        // 64 lanes -> consecutive LDS cols, conflict-free
    const int rb = tid >> 6;        // 0..3
    const int h0 = rb * 4;          // first local output row of this thread

    float acc[4][COUT];
    U<4>::run([&](auto R) {
        U<COUT>::run([&](auto O) {
            acc[decltype(R)::value][decltype(O)::value] = 0.f;
        });
    });

    // cin, dy, j, r: forced compile-time (they feed CL[][] and register-array
    // indices). dx: runtime loop (only feeds LDS/SGPR addresses) -> keeps the
    // body at ~1200 FMA instructions instead of 6000, I$-friendly.
    U<CIN>::run([&](auto CI) {
        constexpr int ci = decltype(CI)::value;
        const float* tp = &tile[(ci * IN_H + h0) * IN_W + w];
        for (int dx = 0; dx < 5; ++dx) {
            // 8 rows of x serve 4 output rows x 5 dy taps
            float xv[8];
            U<8>::run([&](auto RR) {
                xv[decltype(RR)::value] = tp[decltype(RR)::value * IN_W + dx];
            });
            const float* wp = ws + (ci * 5 + dx) * 50;  // wave-uniform -> s_load
            U<5>::run([&](auto DY) {
                constexpr int dy = decltype(DY)::value;
                U<10>::run([&](auto J) {
                    constexpr int j = decltype(J)::value;
                    const float wv = wp[dy * 10 + j];
                    constexpr int o = CL[ci][j];     // folds to a literal
                    U<4>::run([&](auto R) {
                        constexpr int r = decltype(R)::value;
                        acc[r][o] = fmaf(wv, xv[r + dy], acc[r][o]);
                    });
                });
            });
        }
    });

    // ---- Epilogue: add bias, store coalesced dwords ----
    const float* bias = ws + BIAS_OFF;
    float* ob = out + (size_t)b * COUT * HW * HW
                    + (size_t)(bh0 + h0) * HW + (bw0 + w);
    U<COUT>::run([&](auto O) {
        constexpr int o = decltype(O)::value;
        const float bv = bias[o];
        U<4>::run([&](auto R) {
            constexpr int r = decltype(R)::value;
            ob[(size_t)o * HW * HW + (size_t)r * HW] = acc[r][o] + bv;
        });
    });
}

extern "C" void kernel_launch(void* const* d_in, const int* in_sizes, int n_in,
                              void* d_out, int out_size, void* d_ws, size_t ws_size,
                              hipStream_t stream) {
    const float* x    = (const float*)d_in[0];
    const float* W    = (const float*)d_in[1];
    const float* b    = (const float*)d_in[2];
    const int*   mask = (const int*)d_in[3];
    float* ws  = (float*)d_ws;
    float* out = (float*)d_out;

    hipLaunchKernelGGL(pack_weights, dim3(7), dim3(256), 0, stream, W, b, mask, ws);

    dim3 grid(HW / TILE_W, HW / TILE_H, 32);   // 8 x 32 x 32 = 8192 blocks
    hipLaunchKernelGGL(conv_main, grid, dim3(256), 0, stream, x, ws, out);
}

// Round 2
// 932.536 us; speedup vs baseline: 13.4703x; 5.1327x over previous
//
#include <hip/hip_runtime.h>

// LeNet C3 connectivity: for each input channel, the 10 output channels it feeds.
constexpr int CL[6][10] = {
    {0, 4, 5, 6, 9, 10, 11, 12, 14, 15},   // cin 0
    {0, 1, 5, 6, 7, 10, 11, 12, 13, 15},   // cin 1
    {0, 1, 2, 6, 7, 8, 11, 13, 14, 15},    // cin 2
    {1, 2, 3, 6, 7, 8, 9, 12, 14, 15},     // cin 3
    {2, 3, 4, 7, 8, 9, 10, 12, 13, 15},    // cin 4
    {3, 4, 5, 8, 9, 10, 11, 13, 14, 15},   // cin 5
};

#define CIN   6
#define COUT  16
#define HW    512
#define TILE_W 64
#define TILE_H 16
#define IN_W  68   // TILE_W + 4 halo
#define IN_H  20   // TILE_H + 4 halo
#define BIAS_OFF 1536  // float offset of bias within d_ws

// ---- Forced compile-time unrolling machinery -------------------------------
// Round 0: #pragma unroll silently failed -> CL[cin][j] runtime -> acc in
// scratch (VGPR=44, 48 GB spill traffic). Round 1 counters showed the spill
// survived in smaller form: WRITE_SIZE 6.3x output, extra bytes/thread ==
// sizeof(acc)*5 == acc spilled around each runtime-dx back-edge. Fix: NO
// runtime loops at all in compute -- straight-line code, no back-edge for the
// register allocator to split acc's live range around.
template<int V> struct Ic { static constexpr int value = V; };

template<int N> struct U {
    template<class F>
    static __device__ __forceinline__ void run(F&& f) {
        U<N - 1>::run(f);
        f(Ic<N - 1>{});
    }
};
template<> struct U<0> {
    template<class F>
    static __device__ __forceinline__ void run(F&&) {}
};

// Pack masked weights into ws as wpk[cin][dx][dy][j(0..9)] (1500 floats),
// bias at float offset 1536 (16 floats). All-uniform layout so the main
// kernel's weight reads are scalar (SGPR) loads with immediate offsets.
__global__ void pack_weights(const float* __restrict__ W,
                             const float* __restrict__ b,
                             const int* __restrict__ mask,
                             float* __restrict__ ws) {
    int i = blockIdx.x * blockDim.x + threadIdx.x;
    if (i < 1500) {
        int cin = i / 250;
        int r   = i % 250;
        int dx  = r / 50;
        int r2  = r % 50;
        int dy  = r2 / 10;
        int j   = r2 % 10;
        int cout = CL[cin][j];
        float v = W[((cout * CIN + cin) * 5 + dy) * 5 + dx]
                  * (float)mask[cout * CIN + cin];
        ws[((cin * 5 + dx) * 5 + dy) * 10 + j] = v;
    } else if (i >= BIAS_OFF && i < BIAS_OFF + COUT) {
        ws[i] = b[i - BIAS_OFF];
    }
}

__global__ __launch_bounds__(256, 4)   // 4 waves/SIMD: VGPR cap 128, LDS fits 4 blocks/CU
void conv_main(const float* __restrict__ x,
               const float* __restrict__ ws,
               float* __restrict__ out) {
    __shared__ float tile[CIN * IN_H * IN_W];  // 8160 floats = 32640 B

    const int tid = threadIdx.x;
    const int bw0 = blockIdx.x * TILE_W;
    const int bh0 = blockIdx.y * TILE_H;
    const int b   = blockIdx.z;

    // ---- Stage input tile (all 6 channels, with 2-wide zero halo) ----
    const float* xb = x + (size_t)b * CIN * HW * HW;
    for (int idx = tid; idx < CIN * IN_H * IN_W; idx += 256) {
        int c   = idx % IN_W;
        int t   = idx / IN_W;
        int row = t % IN_H;
        int cin = t / IN_H;
        int gh = bh0 + row - 2;
        int gw = bw0 + c - 2;
        float v = 0.f;
        if ((unsigned)gh < (unsigned)HW && (unsigned)gw < (unsigned)HW)
            v = xb[((size_t)cin * HW + gh) * HW + gw];
        tile[idx] = v;
    }
    __syncthreads();

    // ---- Compute: each thread = 1 column (w) x 4 output rows x 16 couts ----
    const int w  = tid & 63;        // 64 lanes -> consecutive LDS cols, conflict-free
    const int rb = tid >> 6;        // 0..3
    const int h0 = rb * 4;          // first local output row of this thread

    float acc[4][COUT];
    U<4>::run([&](auto R) {
        U<COUT>::run([&](auto O) {
            acc[decltype(R)::value][decltype(O)::value] = 0.f;
        });
    });

    // Fully straight-line compute: cin, dx, dy, j, r ALL compile-time.
    // Every LDS read = ds_read_b32 with an immediate offset off ONE base VGPR;
    // every weight read = s_load with an immediate offset off ws.
    const float* tp0 = &tile[h0 * IN_W + w];   // runtime part of the address
    U<CIN>::run([&](auto CI) {
        constexpr int ci = decltype(CI)::value;
        U<5>::run([&](auto DX) {
            constexpr int dx = decltype(DX)::value;
            // 8 rows of x serve 4 output rows x 5 dy taps
            float xv[8];
            U<8>::run([&](auto RR) {
                constexpr int rr = decltype(RR)::value;
                xv[rr] = tp0[ci * IN_H * IN_W + rr * IN_W + dx];  // imm offset
            });
            U<5>::run([&](auto DY) {
                constexpr int dy = decltype(DY)::value;
                U<10>::run([&](auto J) {
                    constexpr int j = decltype(J)::value;
                    const float wv = ws[((ci * 5 + dx) * 5 + dy) * 10 + j];  // s_load imm
                    constexpr int o = CL[ci][j];     // folds to a literal
                    U<4>::run([&](auto R) {
                        constexpr int r = decltype(R)::value;
                        acc[r][o] = fmaf(wv, xv[r + dy], acc[r][o]);
                    });
                });
            });
        });
    });

    // ---- Epilogue: add bias, store coalesced dwords ----
    const float* bias = ws + BIAS_OFF;
    float* ob = out + (size_t)b * COUT * HW * HW
                    + (size_t)(bh0 + h0) * HW + (bw0 + w);
    U<COUT>::run([&](auto O) {
        constexpr int o = decltype(O)::value;
        const float bv = bias[o];
        U<4>::run([&](auto R) {
            constexpr int r = decltype(R)::value;
            ob[(size_t)o * HW * HW + (size_t)r * HW] = acc[r][o] + bv;
        });
    });
}

extern "C" void kernel_launch(void* const* d_in, const int* in_sizes, int n_in,
                              void* d_out, int out_size, void* d_ws, size_t ws_size,
                              hipStream_t stream) {
    const float* x    = (const float*)d_in[0];
    const float* W    = (const float*)d_in[1];
    const float* b    = (const float*)d_in[2];
    const int*   mask = (const int*)d_in[3];
    float* ws  = (float*)d_ws;
    float* out = (float*)d_out;

    hipLaunchKernelGGL(pack_weights, dim3(7), dim3(256), 0, stream, W, b, mask, ws);

    dim3 grid(HW / TILE_W, HW / TILE_H, 32);   // 8 x 32 x 32 = 8192 blocks
    hipLaunchKernelGGL(conv_main, grid, dim3(256), 0, stream, x, ws, out);
}

// Round 3
// 924.083 us; speedup vs baseline: 13.5935x; 1.0091x over previous
//
#include <hip/hip_runtime.h>

// LeNet C3 connectivity: for each input channel, the 10 output channels it feeds.
constexpr int CL[6][10] = {
    {0, 4, 5, 6, 9, 10, 11, 12, 14, 15},   // cin 0
    {0, 1, 5, 6, 7, 10, 11, 12, 13, 15},   // cin 1
    {0, 1, 2, 6, 7, 8, 11, 13, 14, 15},    // cin 2
    {1, 2, 3, 6, 7, 8, 9, 12, 14, 15},     // cin 3
    {2, 3, 4, 7, 8, 9, 10, 12, 13, 15},    // cin 4
    {3, 4, 5, 8, 9, 10, 11, 13, 14, 15},   // cin 5
};

#define CIN   6
#define COUT  16
#define HW    512
#define TILE_W 64
#define TILE_H 16
#define IN_W  68   // TILE_W + 4 halo
#define IN_H  20   // TILE_H + 4 halo
#define BIAS_OFF 1536  // float offset of bias within d_ws

// ---- Forced compile-time unrolling machinery -------------------------------
// R0: #pragma unroll failed -> acc in scratch (VGPR=44, 48 GB spill traffic).
// R1: runtime-dx back-edge -> acc spilled per iteration (WRITE 6.3x output).
// R2: straight-line code fixed spills, but the SCHEDULER re-chunked the body
//     per output channel to minimize pressure (VGPR=44 again, no spills) --
//     re-reading each xv from LDS ~10x (2400 ds_read/thread). LDS pipe
//     (445e3 cyc/SIMD) now exceeds the VALU FMA floor (384e3 cyc/SIMD).
// R3 fix: sched_barrier between (ci,dx) groups, mask = SALU|VMEM_READ|DS_READ
//     (0x124): loads may hoist across (prefetch), FMAs may NOT -> the per-o
//     re-chunking is structurally impossible; 64 accs stay live; xv reads
//     stay at 240/thread.
template<int V> struct Ic { static constexpr int value = V; };

template<int N> struct U {
    template<class F>
    static __device__ __forceinline__ void run(F&& f) {
        U<N - 1>::run(f);
        f(Ic<N - 1>{});
    }
};
template<> struct U<0> {
    template<class F>
    static __device__ __forceinline__ void run(F&&) {}
};

// Pack masked weights into ws as wpk[cin][dx][dy][j(0..9)] (1500 floats),
// bias at float offset 1536 (16 floats). All-uniform layout so the main
// kernel's weight reads are scalar (SGPR) loads with immediate offsets.
__global__ void pack_weights(const float* __restrict__ W,
                             const float* __restrict__ b,
                             const int* __restrict__ mask,
                             float* __restrict__ ws) {
    int i = blockIdx.x * blockDim.x + threadIdx.x;
    if (i < 1500) {
        int cin = i / 250;
        int r   = i % 250;
        int dx  = r / 50;
        int r2  = r % 50;
        int dy  = r2 / 10;
        int j   = r2 % 10;
        int cout = CL[cin][j];
        float v = W[((cout * CIN + cin) * 5 + dy) * 5 + dx]
                  * (float)mask[cout * CIN + cin];
        ws[((cin * 5 + dx) * 5 + dy) * 10 + j] = v;
    } else if (i >= BIAS_OFF && i < BIAS_OFF + COUT) {
        ws[i] = b[i - BIAS_OFF];
    }
}

__global__ __launch_bounds__(256, 4)   // 4 waves/SIMD: VGPR cap 128 (need ~90-110)
void conv_main(const float* __restrict__ x,
               const float* __restrict__ ws,
               float* __restrict__ out) {
    __shared__ float tile[CIN * IN_H * IN_W];  // 8160 floats = 32640 B

    const int tid = threadIdx.x;
    const int bw0 = blockIdx.x * TILE_W;
    const int bh0 = blockIdx.y * TILE_H;
    const int b   = blockIdx.z;

    // ---- Stage input tile (all 6 channels, with 2-wide zero halo) ----
    const float* xb = x + (size_t)b * CIN * HW * HW;
    for (int idx = tid; idx < CIN * IN_H * IN_W; idx += 256) {
        int c   = idx % IN_W;
        int t   = idx / IN_W;
        int row = t % IN_H;
        int cin = t / IN_H;
        int gh = bh0 + row - 2;
        int gw = bw0 + c - 2;
        float v = 0.f;
        if ((unsigned)gh < (unsigned)HW && (unsigned)gw < (unsigned)HW)
            v = xb[((size_t)cin * HW + gh) * HW + gw];
        tile[idx] = v;
    }
    __syncthreads();

    // ---- Compute: each thread = 1 column (w) x 4 output rows x 16 couts ----
    const int w  = tid & 63;        // 64 lanes -> consecutive LDS cols, conflict-free
    const int rb = tid >> 6;        // 0..3
    const int h0 = rb * 4;          // first local output row of this thread

    float acc[4][COUT];
    U<4>::run([&](auto R) {
        U<COUT>::run([&](auto O) {
            acc[decltype(R)::value][decltype(O)::value] = 0.f;
        });
    });

    // Fully straight-line compute: cin, dx, dy, j, r ALL compile-time.
    // Every LDS read = ds_read_b32 with an immediate offset off ONE base VGPR;
    // every weight read = s_load with an immediate offset off ws.
    const float* tp0 = &tile[h0 * IN_W + w];   // runtime part of the address
    U<CIN>::run([&](auto CI) {
        constexpr int ci = decltype(CI)::value;
        U<5>::run([&](auto DX) {
            constexpr int dx = decltype(DX)::value;
            // Group fence: SALU(0x4) | VMEM_READ(0x20) | DS_READ(0x100) may
            // cross (loads prefetch freely); VALU may NOT (FMAs pinned to
            // their group -> no per-o re-chunking, xv shared by all 10 couts).
            __builtin_amdgcn_sched_barrier(0x124);
            // 8 rows of x serve 4 output rows x 5 dy taps
            float xv[8];
            U<8>::run([&](auto RR) {
                constexpr int rr = decltype(RR)::value;
                xv[rr] = tp0[ci * IN_H * IN_W + rr * IN_W + dx];  // imm offset
            });
            U<5>::run([&](auto DY) {
                constexpr int dy = decltype(DY)::value;
                U<10>::run([&](auto J) {
                    constexpr int j = decltype(J)::value;
                    const float wv = ws[((ci * 5 + dx) * 5 + dy) * 10 + j];  // s_load imm
                    constexpr int o = CL[ci][j];     // folds to a literal
                    U<4>::run([&](auto R) {
                        constexpr int r = decltype(R)::value;
                        acc[r][o] = fmaf(wv, xv[r + dy], acc[r][o]);
                    });
                });
            });
        });
    });
    __builtin_amdgcn_sched_barrier(0x124);

    // ---- Epilogue: add bias, store coalesced dwords ----
    const float* bias = ws + BIAS_OFF;
    float* ob = out + (size_t)b * COUT * HW * HW
                    + (size_t)(bh0 + h0) * HW + (bw0 + w);
    U<COUT>::run([&](auto O) {
        constexpr int o = decltype(O)::value;
        const float bv = bias[o];
        U<4>::run([&](auto R) {
            constexpr int r = decltype(R)::value;
            ob[(size_t)o * HW * HW + (size_t)r * HW] = acc[r][o] + bv;
        });
    });
}

extern "C" void kernel_launch(void* const* d_in, const int* in_sizes, int n_in,
                              void* d_out, int out_size, void* d_ws, size_t ws_size,
                              hipStream_t stream) {
    const float* x    = (const float*)d_in[0];
    const float* W    = (const float*)d_in[1];
    const float* b    = (const float*)d_in[2];
    const int*   mask = (const int*)d_in[3];
    float* ws  = (float*)d_ws;
    float* out = (float*)d_out;

    hipLaunchKernelGGL(pack_weights, dim3(7), dim3(256), 0, stream, W, b, mask, ws);

    dim3 grid(HW / TILE_W, HW / TILE_H, 32);   // 8 x 32 x 32 = 8192 blocks
    hipLaunchKernelGGL(conv_main, grid, dim3(256), 0, stream, x, ws, out);
}